// Round 4
// baseline (1075.262 us; speedup 1.0000x reference)
//
#include <hip/hip_runtime.h>
#include <math.h>

#define PI_F 3.14159265358979323846f

__device__ __forceinline__ float gelu_exact(float v) {
    return 0.5f * v * (1.0f + erff(v * 0.70710678118654752f));
}
__device__ __forceinline__ int rfl(int x) { return __builtin_amdgcn_readfirstlane(x); }

// XCD-locality swizzle for 8192-block grids: all 64 ny-blocks of one (b,nx)
// land on the same XCD (assuming blk%8 round-robin XCD dispatch). Bijective.
__device__ __forceinline__ void swz8k(int blk, int& b, int& nx, int& ny) {
    int x = blk & 7;               // xcd
    int j = blk >> 3;              // 0..1023
    int pair = x * 16 + (j >> 6);  // 0..127 = (b,nx)
    ny = j & 63;
    b = pair >> 6;
    nx = pair & 63;
}

// ---------------- emb: embk[b*32+c] = t_emb + c_emb + lift_b ----------------
__global__ void k_emb(const float* __restrict__ time_i, const float* __restrict__ conditions,
                      const float* __restrict__ t_embed_w, const float* __restrict__ t_embed_b,
                      const float* __restrict__ c_embed_w, const float* __restrict__ c_embed_b,
                      const float* __restrict__ lift_b, float* __restrict__ embk) {
    __shared__ float red[8][32];
    int t = threadIdx.x;
    int b = blockIdx.x;
    int c = t & 31, lg = t >> 5;
    float acc = 0.0f;
    if (lg == 0) {
        acc = t_embed_b[c] + c_embed_b[c] + lift_b[c];
        float tv = time_i[b];
        float ang = PI_F * tv;
        const float* tw = t_embed_w + c * 11;
        for (int i = 0; i < 5; i++) {
            float s, co; sincosf(ang, &s, &co);
            acc += co * tw[i] + s * tw[5 + i];
            ang *= 2.0f;
        }
        acc += tv * tw[10];
    }
    const float* cw = c_embed_w + c * 352;
    for (int j = 0; j < 4; j++) {
        int l = lg * 4 + j;
        float v = conditions[b * 32 + l];
        float ang = PI_F * v;
        for (int i = 0; i < 5; i++) {
            float s, co; sincosf(ang, &s, &co);
            acc += co * cw[l * 10 + i] + s * cw[l * 10 + 5 + i];
            ang *= 2.0f;
        }
        acc += v * cw[320 + l];
    }
    red[lg][c] = acc;
    __syncthreads();
    if (t < 32) {
        float s = 0.0f;
        for (int g = 0; g < 8; g++) s += red[g][t];
        embk[b * 32 + t] = s;
    }
}

// ---------------- transpose bypass weights: wtb[l][i][o] = byp_w[l][o][i] ----------------
__global__ void k_wt(const float* __restrict__ byp_w, float* __restrict__ wtb) {
    int idx = blockIdx.x * 256 + threadIdx.x;  // 0..4095
    int l = idx >> 10, rem = idx & 1023;
    int o = rem >> 5, i = rem & 31;
    wtb[(l << 10) + (i << 5) + o] = byp_w[idx];
}

// ------- k_lift: lift conv + emb add, fused forward z-DFT -> a1[b][c][kz][nx][ny] -------
__global__ __launch_bounds__(256) void k_lift(const float* __restrict__ state_in,
        const float* __restrict__ node_pos, const float* __restrict__ lift_w,
        const float* __restrict__ embk, float* __restrict__ x0, float2* __restrict__ a1) {
    __shared__ float ys[32 * 65];
    int t = threadIdx.x;
    int b, nx, ny; swz8k(blockIdx.x, b, nx, ny);
    int nxy = nx * 64 + ny;
    int nz = t & 63;
    int n = (nxy << 6) + nz;
    int wq = rfl(t >> 6);

    float f[37];
    const float4 s4 = *(const float4*)(state_in + ((size_t)b * 262144 + n) * 4);
    f[0] = s4.x; f[1] = s4.y; f[2] = s4.z; f[3] = s4.w;
    const float* pp = node_pos + ((size_t)b * 262144 + n) * 3;
    for (int l = 0; l < 3; l++) {
        float p = pp[l];
        float ang = PI_F * p;
        for (int i = 0; i < 5; i++) {
            float s, co; sincosf(ang, &s, &co);
            f[4 + l * 10 + i] = co;
            f[4 + l * 10 + 5 + i] = s;
            ang *= 2.0f;
        }
        f[34 + l] = p;
    }
    for (int k = 0; k < 8; k++) {
        int o = wq * 8 + k;
        float acc = embk[b * 32 + o];            // s_load
        const float* w = lift_w + o * 37;        // s_load
        #pragma unroll
        for (int q = 0; q < 37; q++) acc += w[q] * f[q];
        x0[(((size_t)(b * 32 + o)) << 18) + n] = acc;
        ys[o * 65 + nz] = acc;
    }
    __syncthreads();
    {   // forward z-DFT: thread (o,kz)
        int o = t >> 3, kz = t & 7;
        float cs, ss; sincosf((float)kz * (PI_F / 32.0f), &ss, &cs);
        float c = 1.0f, s = 0.0f, re = 0.0f, im = 0.0f;
        const float* yr = ys + o * 65;
        for (int n2 = 0; n2 < 64; n2++) {
            float v = yr[n2];
            re += v * c; im -= v * s;
            float nc = c * cs - s * ss; s = s * cs + c * ss; c = nc;
        }
        a1[(((size_t)(b * 32 + o)) * 8 + kz) * 4096 + nxy] = make_float2(re, im);
    }
}

// ------- k_fyx: forward y-DFT + x-DFT per (b,c,kz) plane. a1 -> xft[b][c][kz][ky][kx] -------
__global__ __launch_bounds__(256) void k_fyx(const float2* __restrict__ a1,
                                             float2* __restrict__ xft) {
    __shared__ float pr[64 * 65], pi_[64 * 65];
    __shared__ float a2r[8 * 66], a2i[8 * 66];
    int t = threadIdx.x;
    int bckz = blockIdx.x;           // (b*32+c)*8+kz
    const float2* src = a1 + ((size_t)bckz) * 4096;
    for (int u = 0; u < 16; u++) {
        int idx = u * 256 + t;       // nx*64+ny
        float2 v = src[idx];
        pr[(idx >> 6) * 65 + (idx & 63)] = v.x;
        pi_[(idx >> 6) * 65 + (idx & 63)] = v.y;
    }
    __syncthreads();
    {   // y-DFT: out a2[ky][nx], thread (kyq,nx)
        int nx = t & 63, kyq = t >> 6;
        const float* rr_ = pr + nx * 65;
        const float* ii_ = pi_ + nx * 65;
        for (int h = 0; h < 2; h++) {
            int ky = kyq + h * 4;
            float cs, ss; sincosf((float)ky * (PI_F / 32.0f), &ss, &cs);
            float c = 1.0f, s = 0.0f, rr = 0.0f, ri = 0.0f;
            for (int ny = 0; ny < 64; ny++) {
                float ar = rr_[ny], ai = ii_[ny];
                rr += ar * c + ai * s;
                ri += ai * c - ar * s;
                float nc = c * cs - s * ss; s = s * cs + c * ss; c = nc;
            }
            a2r[ky * 66 + nx] = rr;
            a2i[ky * 66 + nx] = ri;
        }
    }
    __syncthreads();
    if (t < 64) {                    // x-DFT: out xft[ky][kx], t = ky*8+kx
        int ky = t >> 3, kx = t & 7;
        float cs, ss; sincosf((float)kx * (PI_F / 32.0f), &ss, &cs);
        float c = 1.0f, s = 0.0f, rr = 0.0f, ri = 0.0f;
        const float* ar_ = a2r + ky * 66;
        const float* ai_ = a2i + ky * 66;
        for (int nx = 0; nx < 64; nx++) {
            float ar = ar_[nx], ai = ai_[nx];
            rr += ar * c + ai * s;
            ri += ai * c - ar * s;
            float nc = c * cs - s * ss; s = s * cs + c * ss; c = nc;
        }
        xft[((size_t)bckz) * 64 + t] = make_float2(rr, ri);
    }
}

// ---------------- mode mix per (b,kx,ky): yft[o][kz] = sum_i xft[i][kz] * w ----------------
__global__ __launch_bounds__(256) void k_mix(const float2* __restrict__ xft,
        const float* __restrict__ wr, const float* __restrict__ wi,
        float2* __restrict__ yft) {
    __shared__ float2 lx[32 * 8];
    int t = threadIdx.x;
    int b = blockIdx.x >> 6;
    int kx = (blockIdx.x >> 3) & 7;
    int ky = blockIdx.x & 7;
    {
        int i = t >> 3, kz = t & 7;
        lx[t] = xft[((size_t)((b * 32 + i) * 8 + kz)) * 64 + ky * 8 + kx];
    }
    __syncthreads();
    int o = t >> 3, kz = t & 7;
    float yr = 0.0f, yi = 0.0f;
    for (int i = 0; i < 32; i++) {
        float2 x = lx[i * 8 + kz];
        int wofs = ((i * 32 + o) << 9) + kx * 64 + ky * 8 + kz;   // w[i][o][kx][ky][kz]
        float wrv = wr[wofs], wiv = wi[wofs];
        yr += x.x * wrv - x.y * wiv;
        yi += x.x * wiv + x.y * wrv;
    }
    yft[((size_t)((b * 32 + o) * 8 + kz)) * 64 + ky * 8 + kx] = make_float2(yr, yi);
}

// ------- k_ix: inverse-x only. yft -> b1[b][nx][o][kz][ky] (2 MB) -------
__global__ __launch_bounds__(256) void k_ix(const float2* __restrict__ yft,
                                            float2* __restrict__ b1) {
    __shared__ float2 ly[512 * 9];   // [oo*64+kz*8+ky][kx] padded
    int t = threadIdx.x;
    int b  = blockIdx.x >> 8;
    int nx = (blockIdx.x >> 2) & 63;
    int og = blockIdx.x & 3;
    const float2* src = yft + ((size_t)(b * 32 + og * 8)) * 512;
    for (int u = 0; u < 16; u++) {
        int g = u * 256 + t;         // (oo*64+kz*8+ky)*8 + kx
        ly[(g >> 3) * 9 + (g & 7)] = src[g];
    }
    __syncthreads();
    float cs, ss; sincosf((float)nx * (PI_F / 32.0f), &ss, &cs);
    float2* dst = b1 + ((size_t)(b * 64 + nx)) * 2048 + og * 512;
    for (int h = 0; h < 2; h++) {
        int idx = h * 256 + t;       // oo*64 + kz*8 + ky
        const float2* row = ly + idx * 9;
        float c = 1.0f, s = 0.0f, rr = 0.0f, ri = 0.0f;
        #pragma unroll
        for (int kx = 0; kx < 8; kx++) {
            float2 y = row[kx];
            rr += y.x * c - y.y * s;      // e^{+i kx nx θ}
            ri += y.x * s + y.y * c;
            float nc = c * cs - s * ss; s = s * cs + c * ss; c = nc;
        }
        dst[idx] = make_float2(rr, ri);
    }
}

// ------- k_fin v4: inverse-y (from contiguous b1 slice) + bypass + inverse-z + gelu
//         + fused forward z-DFT for the next layer -------
__global__ __launch_bounds__(256) void k_fin(
        const float* __restrict__ xin, const float2* __restrict__ b1,
        const float* __restrict__ wt, const float* __restrict__ bb,
        float* __restrict__ xout, float2* __restrict__ a1, int do_z) {
    __shared__ float xs[32 * 64];
    __shared__ float2 b1s[8 * 264];  // [ky][o*8+kz] padded
    __shared__ float2 ms[256];       // [o*8+kz]
    __shared__ float ys[32 * 65];
    int t = threadIdx.x;
    int b, nx, ny; swz8k(blockIdx.x, b, nx, ny);
    int nxy = nx * 64 + ny;

    const float* xb = xin + (((size_t)b * 32) << 18) + (nxy << 6);
    for (int u = 0; u < 2; u++) {
        int i4 = u * 256 + t;
        int ch = i4 >> 4, q = i4 & 15;
        float4 v = *(const float4*)(xb + ((size_t)ch << 18) + q * 4);
        *(float4*)(xs + ch * 64 + q * 4) = v;
    }
    const float2* bsrc = b1 + ((size_t)(b * 64 + nx)) * 2048;  // contiguous 16 KB, L2-shared
    for (int u = 0; u < 8; u++) {
        int g = u * 256 + t;         // (o*8+kz)*8 + ky
        float2 v = bsrc[g];
        b1s[(g & 7) * 264 + (g >> 3)] = v;
    }
    __syncthreads();
    {   // inverse-y at this ny: thread t = o*8+kz
        float cs, ss; sincosf((float)ny * (PI_F / 32.0f), &ss, &cs);
        float c = 1.0f, s = 0.0f, mr = 0.0f, mi = 0.0f;
        #pragma unroll
        for (int ky = 0; ky < 8; ky++) {
            float2 v = b1s[ky * 264 + t];
            mr += v.x * c - v.y * s;      // e^{+i ky ny θ}
            mi += v.x * s + v.y * c;
            float nc = c * cs - s * ss; s = s * cs + c * ss; c = nc;
        }
        ms[t] = make_float2(mr, mi);
    }
    __syncthreads();

    int nz = t & 63;
    int wq = rfl(t >> 6);
    float c7[8], s7[8];
    c7[0] = 1.f; s7[0] = 0.f;
    {
        float cs, ss; sincosf((float)nz * (PI_F / 32.0f), &ss, &cs);
        #pragma unroll
        for (int kz = 1; kz < 8; kz++) {
            c7[kz] = c7[kz - 1] * cs - s7[kz - 1] * ss;
            s7[kz] = s7[kz - 1] * cs + c7[kz - 1] * ss;
        }
    }
    float acc[8];
    #pragma unroll
    for (int k = 0; k < 8; k++) acc[k] = bb[wq * 8 + k];        // s_load
    #pragma unroll 8
    for (int i = 0; i < 32; i++) {
        float xv = xs[i * 64 + nz];                             // conflict-free ds_read
        const float* wrow = wt + i * 32 + wq * 8;               // s_load_dwordx8
        #pragma unroll
        for (int k = 0; k < 8; k++) acc[k] += wrow[k] * xv;
    }
    const float scale = 1.0f / 262144.0f;
    size_t obase = (((size_t)b * 32) << 18) + (nxy << 6) + nz;
    #pragma unroll
    for (int k = 0; k < 8; k++) {
        int o = wq * 8 + k;
        const float2* mrow = ms + o * 8;                        // wave-uniform LDS
        float sp = mrow[0].x;
        #pragma unroll
        for (int kz = 1; kz < 8; kz++) {
            float2 m = mrow[kz];
            sp += 2.0f * (m.x * c7[kz] - m.y * s7[kz]);
        }
        float g = gelu_exact(sp * scale + acc[k]);
        xout[obase + ((size_t)o << 18)] = g;
        ys[o * 65 + nz] = g;
    }
    if (do_z) {
        __syncthreads();
        int o = t >> 3, kz = t & 7;
        float cs, ss; sincosf((float)kz * (PI_F / 32.0f), &ss, &cs);
        float c = 1.0f, s = 0.0f, re = 0.0f, im = 0.0f;
        const float* yr = ys + o * 65;
        for (int n2 = 0; n2 < 64; n2++) {
            float v = yr[n2];
            re += v * c; im -= v * s;
            float nc = c * cs - s * ss; s = s * cs + c * ss; c = nc;
        }
        a1[(((size_t)(b * 32 + o)) * 8 + kz) * 4096 + nxy] = make_float2(re, im);
    }
}

// ---------------- projection: weights via scalar loads, no LDS ----------------
__global__ void k_proj(const float* __restrict__ x4, const float* __restrict__ w1,
                       const float* __restrict__ b1, const float* __restrict__ w2,
                       const float* __restrict__ b2, const float* __restrict__ state_in,
                       float* __restrict__ out) {
    int t = threadIdx.x;
    int g = blockIdx.x * 256 + t;
    int b = rfl(g >> 18);
    int n = g & (262144 - 1);
    float xv[32];
    const float* xb = x4 + (((size_t)b * 32) << 18) + n;
    #pragma unroll 8
    for (int i = 0; i < 32; i++) xv[i] = xb[(size_t)i << 18];
    float h[32];
    for (int o = 0; o < 32; o++) {
        float a = b1[o];
        const float* w = w1 + o * 32;
        #pragma unroll
        for (int i = 0; i < 32; i++) a += w[i] * xv[i];
        h[o] = gelu_exact(a);
    }
    size_t base = ((size_t)b * 262144 + n) * 4;
    float4 sv = *(const float4*)(state_in + base);
    float r[4];
    for (int j = 0; j < 4; j++) {
        float a = b2[j];
        const float* w = w2 + j * 32;
        #pragma unroll
        for (int o = 0; o < 32; o++) a += w[o] * h[o];
        r[j] = a;
    }
    *(float4*)(out + base) = make_float4(sv.x + 0.05f * r[0], sv.y + 0.05f * r[1],
                                         sv.z + 0.05f * r[2], sv.w + 0.05f * r[3]);
}

extern "C" void kernel_launch(void* const* d_in, const int* in_sizes, int n_in,
                              void* d_out, int out_size, void* d_ws, size_t ws_size,
                              hipStream_t stream) {
    const float* state_in   = (const float*)d_in[0];
    const float* node_pos   = (const float*)d_in[1];
    const float* time_i     = (const float*)d_in[3];
    const float* conditions = (const float*)d_in[4];
    const float* t_embed_w  = (const float*)d_in[5];
    const float* t_embed_b  = (const float*)d_in[6];
    const float* c_embed_w  = (const float*)d_in[7];
    const float* c_embed_b  = (const float*)d_in[8];
    const float* lift_w     = (const float*)d_in[9];
    const float* lift_b     = (const float*)d_in[10];
    const float* spec_wr    = (const float*)d_in[11];
    const float* spec_wi    = (const float*)d_in[12];
    const float* byp_w      = (const float*)d_in[13];
    const float* byp_b      = (const float*)d_in[14];
    const float* proj1_w    = (const float*)d_in[15];
    const float* proj1_b    = (const float*)d_in[16];
    const float* proj2_w    = (const float*)d_in[17];
    const float* proj2_b    = (const float*)d_in[18];
    float* out = (float*)d_out;
    float* ws  = (float*)d_ws;

    float*  xA   = ws;                          // 16777216 floats
    float*  xB   = ws + 16777216;               // 16777216
    float2* a1   = (float2*)(ws + 33554432);    // 2097152 float2 = 4194304 floats
    float2* xft  = (float2*)(ws + 37748736);    // 32768 float2
    float2* yft  = (float2*)(ws + 37814272);    // 32768 float2
    float2* b1   = (float2*)(ws + 37879808);    // 262144 float2 -> ends 38404096
    float*  embk = ws + 38404096;               // 64
    float*  wtb  = ws + 38404160;               // 4096

    k_emb<<<2, 256, 0, stream>>>(time_i, conditions, t_embed_w, t_embed_b,
                                 c_embed_w, c_embed_b, lift_b, embk);
    k_wt<<<16, 256, 0, stream>>>(byp_w, wtb);
    k_lift<<<8192, 256, 0, stream>>>(state_in, node_pos, lift_w, embk, xA, a1);

    for (int l = 0; l < 4; l++) {
        float* xin  = (l & 1) ? xB : xA;
        float* xout = (l & 1) ? xA : xB;
        k_fyx<<<512, 256, 0, stream>>>(a1, xft);
        k_mix<<<128, 256, 0, stream>>>(xft, spec_wr + (size_t)l * 524288,
                                       spec_wi + (size_t)l * 524288, yft);
        k_ix<<<512, 256, 0, stream>>>(yft, b1);
        k_fin<<<8192, 256, 0, stream>>>(xin, b1, wtb + l * 1024, byp_b + l * 32,
                                        xout, a1, (l < 3) ? 1 : 0);
    }

    k_proj<<<2048, 256, 0, stream>>>(xA, proj1_w, proj1_b, proj2_w, proj2_b, state_in, out);
}

// Round 5
// 579.922 us; speedup vs baseline: 1.8541x; 1.8541x over previous
//
#include <hip/hip_runtime.h>
#include <math.h>

#define PI_F 3.14159265358979323846f

__device__ __forceinline__ float gelu_exact(float v) {
    return 0.5f * v * (1.0f + erff(v * 0.70710678118654752f));
}
__device__ __forceinline__ int rfl(int x) { return __builtin_amdgcn_readfirstlane(x); }

// XCD-locality swizzle for 8192-block grids: all 64 ny-blocks of one (b,nx)
// land on the same XCD (assuming blk%8 round-robin XCD dispatch). Bijective.
__device__ __forceinline__ void swz8k(int blk, int& b, int& nx, int& ny) {
    int x = blk & 7;               // xcd
    int j = blk >> 3;              // 0..1023
    int pair = x * 16 + (j >> 6);  // 0..127 = (b,nx)
    ny = j & 63;
    b = pair >> 6;
    nx = pair & 63;
}

// ---------------- emb: embk[b*32+c] = t_emb + c_emb + lift_b ----------------
__global__ void k_emb(const float* __restrict__ time_i, const float* __restrict__ conditions,
                      const float* __restrict__ t_embed_w, const float* __restrict__ t_embed_b,
                      const float* __restrict__ c_embed_w, const float* __restrict__ c_embed_b,
                      const float* __restrict__ lift_b, float* __restrict__ embk) {
    __shared__ float red[8][32];
    int t = threadIdx.x;
    int b = blockIdx.x;
    int c = t & 31, lg = t >> 5;
    float acc = 0.0f;
    if (lg == 0) {
        acc = t_embed_b[c] + c_embed_b[c] + lift_b[c];
        float tv = time_i[b];
        float ang = PI_F * tv;
        const float* tw = t_embed_w + c * 11;
        for (int i = 0; i < 5; i++) {
            float s, co; sincosf(ang, &s, &co);
            acc += co * tw[i] + s * tw[5 + i];
            ang *= 2.0f;
        }
        acc += tv * tw[10];
    }
    const float* cw = c_embed_w + c * 352;
    for (int j = 0; j < 4; j++) {
        int l = lg * 4 + j;
        float v = conditions[b * 32 + l];
        float ang = PI_F * v;
        for (int i = 0; i < 5; i++) {
            float s, co; sincosf(ang, &s, &co);
            acc += co * cw[l * 10 + i] + s * cw[l * 10 + 5 + i];
            ang *= 2.0f;
        }
        acc += v * cw[320 + l];
    }
    red[lg][c] = acc;
    __syncthreads();
    if (t < 32) {
        float s = 0.0f;
        for (int g = 0; g < 8; g++) s += red[g][t];
        embk[b * 32 + t] = s;
    }
}

// -------- k_wt: transpose byp (wtb[l][i][o]) and lift (wlT[q][o]) weights --------
__global__ void k_wt(const float* __restrict__ byp_w, const float* __restrict__ lift_w,
                     float* __restrict__ wtb, float* __restrict__ wlT) {
    int idx = blockIdx.x * 256 + threadIdx.x;
    if (idx < 4096) {
        int l = idx >> 10, rem = idx & 1023;
        int o = rem >> 5, i = rem & 31;
        wtb[(l << 10) + (i << 5) + o] = byp_w[idx];
    } else if (idx < 4096 + 1184) {
        int j = idx - 4096;          // q*32 + o
        int q = j >> 5, o = j & 31;
        wlT[j] = lift_w[o * 37 + q];
    }
}

// ------- k_lift: lift conv + emb, fused forward z-DFT -> a1[b][nxy][o*8+kz] -------
// Features computed ONCE per column by wave 0 into LDS (no per-thread f[37] -> no spill).
__global__ __launch_bounds__(256) void k_lift(const float* __restrict__ state_in,
        const float* __restrict__ node_pos, const float* __restrict__ wlT,
        const float* __restrict__ embk, float* __restrict__ x0, float2* __restrict__ a1) {
    __shared__ float fs[37 * 64];    // [q][nz]
    __shared__ float ys[32 * 65];    // [o][nz]
    int t = threadIdx.x;
    int b, nx, ny; swz8k(blockIdx.x, b, nx, ny);
    int nxy = nx * 64 + ny;

    if (t < 64) {
        int n = (nxy << 6) + t;
        const float4 s4 = *(const float4*)(state_in + ((size_t)b * 262144 + n) * 4);
        fs[0 * 64 + t] = s4.x; fs[1 * 64 + t] = s4.y;
        fs[2 * 64 + t] = s4.z; fs[3 * 64 + t] = s4.w;
        const float* pp = node_pos + ((size_t)b * 262144 + n) * 3;
        for (int l = 0; l < 3; l++) {
            float p = pp[l];
            float ang = PI_F * p;
            for (int i = 0; i < 5; i++) {
                float s, co; sincosf(ang, &s, &co);
                fs[(4 + l * 10 + i) * 64 + t] = co;
                fs[(4 + l * 10 + 5 + i) * 64 + t] = s;
                ang *= 2.0f;
            }
            fs[(34 + l) * 64 + t] = p;
        }
    }
    __syncthreads();

    int nz = t & 63;
    int wq = rfl(t >> 6);
    float acc[8];
    #pragma unroll
    for (int k = 0; k < 8; k++) acc[k] = embk[b * 32 + wq * 8 + k];   // s_load
    #pragma unroll
    for (int q = 0; q < 37; q++) {
        float fq = fs[q * 64 + nz];                  // stride-1 ds_read
        const float* w = wlT + q * 32 + wq * 8;      // s_load_dwordx8
        #pragma unroll
        for (int k = 0; k < 8; k++) acc[k] += w[k] * fq;
    }
    int n = (nxy << 6) + nz;
    #pragma unroll
    for (int k = 0; k < 8; k++) {
        int o = wq * 8 + k;
        x0[(((size_t)(b * 32 + o)) << 18) + n] = acc[k];
        ys[o * 65 + nz] = acc[k];
    }
    __syncthreads();
    {   // forward z-DFT tail: thread t -> (o = t>>3, kz = t&7)
        int o = t >> 3, kz = t & 7;
        float cs, ss; sincosf((float)kz * (PI_F / 32.0f), &ss, &cs);
        float c = 1.0f, s = 0.0f, re = 0.0f, im = 0.0f;
        const float* yr = ys + o * 65;
        for (int n2 = 0; n2 < 64; n2++) {
            float v = yr[n2];
            re += v * c; im -= v * s;
            float nc = c * cs - s * ss; s = s * cs + c * ss; c = nc;
        }
        a1[((size_t)(b * 4096 + nxy)) * 256 + t] = make_float2(re, im);   // coalesced 2 KB
    }
}

// ------- k_fy: forward y-DFT. block=(b,nx), coalesced a1 rows -> a2[b][nx][jj][ky] -------
__global__ __launch_bounds__(256) void k_fy(const float2* __restrict__ a1,
                                            float2* __restrict__ a2) {
    int t = threadIdx.x;
    int blk = blockIdx.x;                     // 128
    int pair = (blk & 7) * 16 + (blk >> 3);   // XCD-matched to producer swizzle
    const float2* src = a1 + ((size_t)pair * 4096) * 64 + t;   // (pair*64 rows)*... see below
    // pair = b*64+nx ; row base = (b*4096 + nx*64 + ny)*256 = (pair*64 + ny)*256
    src = a1 + ((size_t)pair * 64) * 256 + t;
    float accr[8], acci[8];
    #pragma unroll
    for (int k = 0; k < 8; k++) { accr[k] = 0.0f; acci[k] = 0.0f; }
    const float bc = 0.99518472667f;          // cos(pi/32)
    const float bs = -0.09801714033f;         // -sin(pi/32)  (e^{-i pi/32})
    float wc = 1.0f, ws = 0.0f;               // e^{-i ny pi/32}
    #pragma unroll 4
    for (int ny = 0; ny < 64; ny++) {
        float2 v = src[(size_t)ny * 256];
        accr[0] += v.x; acci[0] += v.y;
        float tc = wc, ts = ws;
        #pragma unroll
        for (int ky = 1; ky < 8; ky++) {
            accr[ky] += v.x * tc - v.y * ts;
            acci[ky] += v.x * ts + v.y * tc;
            float nt = tc * wc - ts * ws; ts = ts * wc + tc * ws; tc = nt;
        }
        float nw = wc * bc - ws * bs; ws = ws * bc + wc * bs; wc = nw;
    }
    float4* dst = (float4*)(a2 + ((size_t)(pair * 256 + t)) * 8);
    #pragma unroll
    for (int j = 0; j < 4; j++)
        dst[j] = make_float4(accr[2 * j], acci[2 * j], accr[2 * j + 1], acci[2 * j + 1]);
}

// ------- k_fx: forward x-DFT. block=(b,c): a2 -> xft[b][c][kz][ky][kx] -------
__global__ __launch_bounds__(256) void k_fx(const float2* __restrict__ a2,
                                            float2* __restrict__ xft) {
    __shared__ float lsr[4096], lsi[4096];    // [nx][kz*8+ky]
    int t = threadIdx.x;
    int b = blockIdx.x >> 5, c = blockIdx.x & 31;
    for (int u = 0; u < 16; u++) {
        int idx = u * 256 + t;                // nx*64 + kk
        int nx = idx >> 6, kk = idx & 63;
        float2 v = a2[((size_t)((b * 64 + nx) * 256 + c * 8)) * 8 + kk];
        lsr[idx] = v.x; lsi[idx] = v.y;
    }
    __syncthreads();
    for (int h = 0; h < 2; h++) {
        int f = h * 256 + t;                  // kz*64 + ky*8 + kx
        int kx = f & 7, kzky = f >> 3;
        float sn, cc; sincosf((float)kx * (PI_F / 32.0f), &sn, &cc);
        float bsn = -sn;                      // e^{-i kx pi/32}
        float tc = 1.0f, ts = 0.0f, rr = 0.0f, ri = 0.0f;
        for (int nx = 0; nx < 64; nx++) {
            float vr = lsr[nx * 64 + kzky], vi = lsi[nx * 64 + kzky];
            rr += vr * tc - vi * ts;
            ri += vr * ts + vi * tc;
            float nt = tc * cc - ts * bsn; ts = ts * cc + tc * bsn; tc = nt;
        }
        xft[((size_t)(b * 32 + c)) * 512 + f] = make_float2(rr, ri);
    }
}

// ---------------- mode mix per (b,kx,ky) ----------------
__global__ __launch_bounds__(256) void k_mix(const float2* __restrict__ xft,
        const float* __restrict__ wr, const float* __restrict__ wi,
        float2* __restrict__ yft) {
    __shared__ float2 lx[32 * 8];
    int t = threadIdx.x;
    int b = blockIdx.x >> 6;
    int kx = (blockIdx.x >> 3) & 7;
    int ky = blockIdx.x & 7;
    {
        int i = t >> 3, kz = t & 7;
        lx[t] = xft[((size_t)(b * 32 + i)) * 512 + kz * 64 + ky * 8 + kx];
    }
    __syncthreads();
    int o = t >> 3, kz = t & 7;
    float yr = 0.0f, yi = 0.0f;
    for (int i = 0; i < 32; i++) {
        float2 x = lx[i * 8 + kz];
        int wofs = ((i * 32 + o) << 9) + kx * 64 + ky * 8 + kz;   // w[i][o][kx][ky][kz]
        float wrv = wr[wofs], wiv = wi[wofs];
        yr += x.x * wrv - x.y * wiv;
        yi += x.x * wiv + x.y * wrv;
    }
    yft[((size_t)(b * 32 + o)) * 512 + kz * 64 + ky * 8 + kx] = make_float2(yr, yi);
}

// ------- k_ix: inverse-x only. yft -> b1[b][nx][o][kz][ky] (2 MB) -------
__global__ __launch_bounds__(256) void k_ix(const float2* __restrict__ yft,
                                            float2* __restrict__ b1) {
    __shared__ float2 ly[512 * 9];   // [oo*64+kz*8+ky][kx] padded
    int t = threadIdx.x;
    int b  = blockIdx.x >> 8;
    int nx = (blockIdx.x >> 2) & 63;
    int og = blockIdx.x & 3;
    const float2* src = yft + ((size_t)(b * 32 + og * 8)) * 512;
    for (int u = 0; u < 16; u++) {
        int g = u * 256 + t;         // (oo*64+kz*8+ky)*8 + kx
        ly[(g >> 3) * 9 + (g & 7)] = src[g];
    }
    __syncthreads();
    float cs, ss; sincosf((float)nx * (PI_F / 32.0f), &ss, &cs);
    float2* dst = b1 + ((size_t)(b * 64 + nx)) * 2048 + og * 512;
    for (int h = 0; h < 2; h++) {
        int idx = h * 256 + t;       // oo*64 + kz*8 + ky
        const float2* row = ly + idx * 9;
        float c = 1.0f, s = 0.0f, rr = 0.0f, ri = 0.0f;
        #pragma unroll
        for (int kx = 0; kx < 8; kx++) {
            float2 y = row[kx];
            rr += y.x * c - y.y * s;      // e^{+i kx nx θ}
            ri += y.x * s + y.y * c;
            float nc = c * cs - s * ss; s = s * cs + c * ss; c = nc;
        }
        dst[idx] = make_float2(rr, ri);
    }
}

// ------- k_fin: inverse-y (contiguous b1 slice) + bypass + inverse-z + gelu
//         + fused forward z-DFT for next layer (coalesced a1 write) -------
__global__ __launch_bounds__(256) void k_fin(
        const float* __restrict__ xin, const float2* __restrict__ b1,
        const float* __restrict__ wt, const float* __restrict__ bb,
        float* __restrict__ xout, float2* __restrict__ a1, int do_z) {
    __shared__ float xs[32 * 64];
    __shared__ float b1sr[8 * 264], b1si[8 * 264];   // [ky][o*8+kz]
    __shared__ float2 ms[256];                       // [o*8+kz]
    __shared__ float ys[32 * 65];
    int t = threadIdx.x;
    int b, nx, ny; swz8k(blockIdx.x, b, nx, ny);
    int nxy = nx * 64 + ny;

    const float* xb = xin + (((size_t)b * 32) << 18) + (nxy << 6);
    for (int u = 0; u < 2; u++) {
        int i4 = u * 256 + t;
        int ch = i4 >> 4, q = i4 & 15;
        float4 v = *(const float4*)(xb + ((size_t)ch << 18) + q * 4);
        *(float4*)(xs + ch * 64 + q * 4) = v;
    }
    const float2* bsrc = b1 + ((size_t)(b * 64 + nx)) * 2048;  // contiguous 16 KB
    for (int u = 0; u < 8; u++) {
        int g = u * 256 + t;         // (o*8+kz)*8 + ky
        float2 v = bsrc[g];
        int ky = g & 7, okz = g >> 3;
        b1sr[ky * 264 + okz] = v.x;
        b1si[ky * 264 + okz] = v.y;
    }
    __syncthreads();
    {   // inverse-y at this ny: thread t = o*8+kz
        float cs, ss; sincosf((float)ny * (PI_F / 32.0f), &ss, &cs);
        float c = 1.0f, s = 0.0f, mr = 0.0f, mi = 0.0f;
        #pragma unroll
        for (int ky = 0; ky < 8; ky++) {
            float vr = b1sr[ky * 264 + t], vi = b1si[ky * 264 + t];
            mr += vr * c - vi * s;        // e^{+i ky ny θ}
            mi += vr * s + vi * c;
            float nc = c * cs - s * ss; s = s * cs + c * ss; c = nc;
        }
        ms[t] = make_float2(mr, mi);
    }
    __syncthreads();

    int nz = t & 63;
    int wq = rfl(t >> 6);
    float c7[8], s7[8];
    c7[0] = 1.f; s7[0] = 0.f;
    {
        float cs, ss; sincosf((float)nz * (PI_F / 32.0f), &ss, &cs);
        #pragma unroll
        for (int kz = 1; kz < 8; kz++) {
            c7[kz] = c7[kz - 1] * cs - s7[kz - 1] * ss;
            s7[kz] = s7[kz - 1] * cs + c7[kz - 1] * ss;
        }
    }
    float acc[8];
    #pragma unroll
    for (int k = 0; k < 8; k++) acc[k] = bb[wq * 8 + k];        // s_load
    #pragma unroll 8
    for (int i = 0; i < 32; i++) {
        float xv = xs[i * 64 + nz];                             // conflict-free ds_read
        const float* wrow = wt + i * 32 + wq * 8;               // s_load_dwordx8
        #pragma unroll
        for (int k = 0; k < 8; k++) acc[k] += wrow[k] * xv;
    }
    const float scale = 1.0f / 262144.0f;
    size_t obase = (((size_t)b * 32) << 18) + (nxy << 6) + nz;
    #pragma unroll
    for (int k = 0; k < 8; k++) {
        int o = wq * 8 + k;
        const float2* mrow = ms + o * 8;                        // wave-uniform LDS
        float sp = mrow[0].x;
        #pragma unroll
        for (int kz = 1; kz < 8; kz++) {
            float2 m = mrow[kz];
            sp += 2.0f * (m.x * c7[kz] - m.y * s7[kz]);
        }
        float g = gelu_exact(sp * scale + acc[k]);
        xout[obase + ((size_t)o << 18)] = g;
        ys[o * 65 + nz] = g;
    }
    if (do_z) {
        __syncthreads();
        int o = t >> 3, kz = t & 7;
        float cs, ss; sincosf((float)kz * (PI_F / 32.0f), &ss, &cs);
        float c = 1.0f, s = 0.0f, re = 0.0f, im = 0.0f;
        const float* yr = ys + o * 65;
        for (int n2 = 0; n2 < 64; n2++) {
            float v = yr[n2];
            re += v * c; im -= v * s;
            float nc = c * cs - s * ss; s = s * cs + c * ss; c = nc;
        }
        a1[((size_t)(b * 4096 + nxy)) * 256 + t] = make_float2(re, im);   // coalesced
    }
}

// ---------------- projection: weights via scalar loads, no LDS ----------------
__global__ void k_proj(const float* __restrict__ x4, const float* __restrict__ w1,
                       const float* __restrict__ b1, const float* __restrict__ w2,
                       const float* __restrict__ b2, const float* __restrict__ state_in,
                       float* __restrict__ out) {
    int t = threadIdx.x;
    int g = blockIdx.x * 256 + t;
    int b = rfl(g >> 18);
    int n = g & (262144 - 1);
    float xv[32];
    const float* xb = x4 + (((size_t)b * 32) << 18) + n;
    #pragma unroll 8
    for (int i = 0; i < 32; i++) xv[i] = xb[(size_t)i << 18];
    float h[32];
    for (int o = 0; o < 32; o++) {
        float a = b1[o];
        const float* w = w1 + o * 32;
        #pragma unroll
        for (int i = 0; i < 32; i++) a += w[i] * xv[i];
        h[o] = gelu_exact(a);
    }
    size_t base = ((size_t)b * 262144 + n) * 4;
    float4 sv = *(const float4*)(state_in + base);
    float r[4];
    for (int j = 0; j < 4; j++) {
        float a = b2[j];
        const float* w = w2 + j * 32;
        #pragma unroll
        for (int o = 0; o < 32; o++) a += w[o] * h[o];
        r[j] = a;
    }
    *(float4*)(out + base) = make_float4(sv.x + 0.05f * r[0], sv.y + 0.05f * r[1],
                                         sv.z + 0.05f * r[2], sv.w + 0.05f * r[3]);
}

extern "C" void kernel_launch(void* const* d_in, const int* in_sizes, int n_in,
                              void* d_out, int out_size, void* d_ws, size_t ws_size,
                              hipStream_t stream) {
    const float* state_in   = (const float*)d_in[0];
    const float* node_pos   = (const float*)d_in[1];
    const float* time_i     = (const float*)d_in[3];
    const float* conditions = (const float*)d_in[4];
    const float* t_embed_w  = (const float*)d_in[5];
    const float* t_embed_b  = (const float*)d_in[6];
    const float* c_embed_w  = (const float*)d_in[7];
    const float* c_embed_b  = (const float*)d_in[8];
    const float* lift_w     = (const float*)d_in[9];
    const float* lift_b     = (const float*)d_in[10];
    const float* spec_wr    = (const float*)d_in[11];
    const float* spec_wi    = (const float*)d_in[12];
    const float* byp_w      = (const float*)d_in[13];
    const float* byp_b      = (const float*)d_in[14];
    const float* proj1_w    = (const float*)d_in[15];
    const float* proj1_b    = (const float*)d_in[16];
    const float* proj2_w    = (const float*)d_in[17];
    const float* proj2_b    = (const float*)d_in[18];
    float* out = (float*)d_out;
    float* ws  = (float*)d_ws;

    float*  xA   = ws;                          // 16777216 floats
    float*  xB   = ws + 16777216;               // 16777216
    float2* a1   = (float2*)(ws + 33554432);    // 2097152 float2 -> ends 37748736
    float2* xft  = (float2*)(ws + 37748736);    // 32768 float2
    float2* yft  = (float2*)(ws + 37814272);    // 32768 float2
    float2* b1   = (float2*)(ws + 37879808);    // 262144 float2 -> ends 38404096
    float*  embk = ws + 38404096;               // 64
    float*  wtb  = ws + 38404160;               // 4096 -> 38408256
    float*  wlT  = ws + 38408256;               // 1184 -> 38409440
    float2* a2   = (float2*)(ws + 38409440);    // 262144 float2 -> ends 38933728

    k_emb<<<2, 256, 0, stream>>>(time_i, conditions, t_embed_w, t_embed_b,
                                 c_embed_w, c_embed_b, lift_b, embk);
    k_wt<<<21, 256, 0, stream>>>(byp_w, lift_w, wtb, wlT);
    k_lift<<<8192, 256, 0, stream>>>(state_in, node_pos, wlT, embk, xA, a1);

    for (int l = 0; l < 4; l++) {
        float* xin  = (l & 1) ? xB : xA;
        float* xout = (l & 1) ? xA : xB;
        k_fy<<<128, 256, 0, stream>>>(a1, a2);
        k_fx<<<64, 256, 0, stream>>>(a2, xft);
        k_mix<<<128, 256, 0, stream>>>(xft, spec_wr + (size_t)l * 524288,
                                       spec_wi + (size_t)l * 524288, yft);
        k_ix<<<512, 256, 0, stream>>>(yft, b1);
        k_fin<<<8192, 256, 0, stream>>>(xin, b1, wtb + l * 1024, byp_b + l * 32,
                                        xout, a1, (l < 3) ? 1 : 0);
    }

    k_proj<<<2048, 256, 0, stream>>>(xA, proj1_w, proj1_b, proj2_w, proj2_b, state_in, out);
}

// Round 6
// 548.779 us; speedup vs baseline: 1.9594x; 1.0568x over previous
//
#include <hip/hip_runtime.h>
#include <math.h>

#define PI_F 3.14159265358979323846f

__device__ __forceinline__ float gelu_exact(float v) {
    return 0.5f * v * (1.0f + erff(v * 0.70710678118654752f));
}
__device__ __forceinline__ int rfl(int x) { return __builtin_amdgcn_readfirstlane(x); }

// XCD-locality swizzle for 8192-block grids: all 64 ny-blocks of one (b,nx)
// land on the same XCD (assuming blk%8 round-robin XCD dispatch). Bijective.
__device__ __forceinline__ void swz8k(int blk, int& b, int& nx, int& ny) {
    int x = blk & 7;               // xcd
    int j = blk >> 3;              // 0..1023
    int pair = x * 16 + (j >> 6);  // 0..127 = (b,nx)
    ny = j & 63;
    b = pair >> 6;
    nx = pair & 63;
}

// Radix-8 stage A: 8-point real-input DFT (ω = e^{-iπ/4}); h[0..7] -> H[0..7],
// written to hr/hi at [o][j][q] with o-pitch 67 (bank-safe). ~27 VALU ops.
__device__ __forceinline__ void rdft8(const float h[8], float* __restrict__ hr,
                                      float* __restrict__ hi, int o, int q) {
    const float s2 = 0.70710678118654752f;
    float e0 = h[0] + h[4], e1 = h[1] + h[5], e2 = h[2] + h[6], e3 = h[3] + h[7];
    float o0 = h[0] - h[4], o1 = h[1] - h[5], o2 = h[2] - h[6], o3 = h[3] - h[7];
    float ee = e0 + e2, eo = e1 + e3;
    float H0r = ee + eo, H4r = ee - eo;
    float H2r = e0 - e2, H2i = -(e1 - e3);
    float t13p = s2 * (o1 + o3), t13m = s2 * (o1 - o3);
    float H1r = o0 + t13m, H1i = -o2 - t13p;
    float H3r = o0 - t13m, H3i =  o2 - t13p;
    int base = o * 67 + q;
    hr[base + 0 * 8] = H0r;  hi[base + 0 * 8] = 0.0f;
    hr[base + 1 * 8] = H1r;  hi[base + 1 * 8] = H1i;
    hr[base + 2 * 8] = H2r;  hi[base + 2 * 8] = H2i;
    hr[base + 3 * 8] = H3r;  hi[base + 3 * 8] = H3i;
    hr[base + 4 * 8] = H4r;  hi[base + 4 * 8] = 0.0f;
    hr[base + 5 * 8] = H3r;  hi[base + 5 * 8] = -H3i;
    hr[base + 6 * 8] = H2r;  hi[base + 6 * 8] = -H2i;
    hr[base + 7 * 8] = H1r;  hi[base + 7 * 8] = -H1i;
}

// Radix-8 stage B: A[kz] = sum_q H_q[kz] e^{-i kz q π/32}. ~85 VALU ops.
__device__ __forceinline__ float2 zdft_combine(const float* __restrict__ hr,
                                               const float* __restrict__ hi,
                                               int o, int kz) {
    float cs, ss; sincosf((float)kz * (PI_F / 32.0f), &ss, &cs);
    float c = 1.0f, s = 0.0f, re = 0.0f, im = 0.0f;
    int base = o * 67 + kz * 8;
    #pragma unroll
    for (int q = 0; q < 8; q++) {
        float Hr = hr[base + q], Hi = hi[base + q];
        re += Hr * c + Hi * s;          // H * e^{-i kz q θ}
        im += Hi * c - Hr * s;
        float nc = c * cs - s * ss; s = s * cs + c * ss; c = nc;
    }
    return make_float2(re, im);
}

// ---------------- emb: embk[b*32+c] = t_emb + c_emb + lift_b ----------------
__global__ void k_emb(const float* __restrict__ time_i, const float* __restrict__ conditions,
                      const float* __restrict__ t_embed_w, const float* __restrict__ t_embed_b,
                      const float* __restrict__ c_embed_w, const float* __restrict__ c_embed_b,
                      const float* __restrict__ lift_b, float* __restrict__ embk) {
    __shared__ float red[8][32];
    int t = threadIdx.x;
    int b = blockIdx.x;
    int c = t & 31, lg = t >> 5;
    float acc = 0.0f;
    if (lg == 0) {
        acc = t_embed_b[c] + c_embed_b[c] + lift_b[c];
        float tv = time_i[b];
        float ang = PI_F * tv;
        const float* tw = t_embed_w + c * 11;
        for (int i = 0; i < 5; i++) {
            float s, co; sincosf(ang, &s, &co);
            acc += co * tw[i] + s * tw[5 + i];
            ang *= 2.0f;
        }
        acc += tv * tw[10];
    }
    const float* cw = c_embed_w + c * 352;
    for (int j = 0; j < 4; j++) {
        int l = lg * 4 + j;
        float v = conditions[b * 32 + l];
        float ang = PI_F * v;
        for (int i = 0; i < 5; i++) {
            float s, co; sincosf(ang, &s, &co);
            acc += co * cw[l * 10 + i] + s * cw[l * 10 + 5 + i];
            ang *= 2.0f;
        }
        acc += v * cw[320 + l];
    }
    red[lg][c] = acc;
    __syncthreads();
    if (t < 32) {
        float s = 0.0f;
        for (int g = 0; g < 8; g++) s += red[g][t];
        embk[b * 32 + t] = s;
    }
}

// -------- k_wt: transpose byp (wtb[l][i][o]) and lift (wlT[q][o]) weights --------
__global__ void k_wt(const float* __restrict__ byp_w, const float* __restrict__ lift_w,
                     float* __restrict__ wtb, float* __restrict__ wlT) {
    int idx = blockIdx.x * 256 + threadIdx.x;
    if (idx < 4096) {
        int l = idx >> 10, rem = idx & 1023;
        int o = rem >> 5, i = rem & 31;
        wtb[(l << 10) + (i << 5) + o] = byp_w[idx];
    } else if (idx < 4096 + 1184) {
        int j = idx - 4096;          // q*32 + o
        int q = j >> 5, o = j & 31;
        wlT[j] = lift_w[o * 37 + q];
    }
}

// ------- k_lift: lift conv + emb, radix-8 forward z-DFT -> a1[b][nxy][o*8+kz] -------
__global__ __launch_bounds__(256) void k_lift(const float* __restrict__ state_in,
        const float* __restrict__ node_pos, const float* __restrict__ wlT,
        const float* __restrict__ embk, float* __restrict__ x0, float2* __restrict__ a1) {
    __shared__ float S[8832];
    float* fs = S;                   // 37*64 = 2368   [q][nz]
    float* ys = S + 2368;            // 32*68 = 2176   [o][nz] pitch 68
    float* hr = S + 4544;            // 2144           [o][j][q] pitch 67
    float* hi = S + 6688;            // 2144
    int t = threadIdx.x;
    int b, nx, ny; swz8k(blockIdx.x, b, nx, ny);
    int nxy = nx * 64 + ny;

    if (t < 64) {
        int n = (nxy << 6) + t;
        const float4 s4 = *(const float4*)(state_in + ((size_t)b * 262144 + n) * 4);
        fs[0 * 64 + t] = s4.x; fs[1 * 64 + t] = s4.y;
        fs[2 * 64 + t] = s4.z; fs[3 * 64 + t] = s4.w;
        const float* pp = node_pos + ((size_t)b * 262144 + n) * 3;
        for (int l = 0; l < 3; l++) {
            float p = pp[l];
            float ang = PI_F * p;
            for (int i = 0; i < 5; i++) {
                float s, co; sincosf(ang, &s, &co);
                fs[(4 + l * 10 + i) * 64 + t] = co;
                fs[(4 + l * 10 + 5 + i) * 64 + t] = s;
                ang *= 2.0f;
            }
            fs[(34 + l) * 64 + t] = p;
        }
    }
    __syncthreads();

    int nz = t & 63;
    int wq = rfl(t >> 6);
    float acc[8];
    #pragma unroll
    for (int k = 0; k < 8; k++) acc[k] = embk[b * 32 + wq * 8 + k];   // s_load
    #pragma unroll
    for (int q = 0; q < 37; q++) {
        float fq = fs[q * 64 + nz];                  // stride-1 ds_read
        const float* w = wlT + q * 32 + wq * 8;      // s_load_dwordx8
        #pragma unroll
        for (int k = 0; k < 8; k++) acc[k] += w[k] * fq;
    }
    int n = (nxy << 6) + nz;
    #pragma unroll
    for (int k = 0; k < 8; k++) {
        int o = wq * 8 + k;
        x0[(((size_t)(b * 32 + o)) << 18) + n] = acc[k];
        ys[o * 68 + nz] = acc[k];
    }
    __syncthreads();
    {   // radix-8 stage A: thread (o = t>>3, q = t&7)
        int o = t >> 3, q = t & 7;
        float h[8];
        #pragma unroll
        for (int p = 0; p < 8; p++) h[p] = ys[o * 68 + 8 * p + q];
        rdft8(h, hr, hi, o, q);
    }
    __syncthreads();
    {   // stage B: thread (o = t>>3, kz = t&7)
        float2 r = zdft_combine(hr, hi, t >> 3, t & 7);
        a1[((size_t)(b * 4096 + nxy)) * 256 + t] = r;   // coalesced 2 KB
    }
}

// ------- k_fy: forward y-DFT. block=(b,nx), coalesced a1 rows -> a2[b][nx][jj][ky] -------
__global__ __launch_bounds__(256) void k_fy(const float2* __restrict__ a1,
                                            float2* __restrict__ a2) {
    int t = threadIdx.x;
    int blk = blockIdx.x;                     // 128
    int pair = (blk & 7) * 16 + (blk >> 3);   // XCD-matched to producer swizzle
    const float2* src = a1 + ((size_t)pair * 64) * 256 + t;
    float accr[8], acci[8];
    #pragma unroll
    for (int k = 0; k < 8; k++) { accr[k] = 0.0f; acci[k] = 0.0f; }
    const float bc = 0.99518472667f;          // cos(pi/32)
    const float bs = -0.09801714033f;         // -sin(pi/32)  (e^{-i pi/32})
    float wc = 1.0f, ws = 0.0f;               // e^{-i ny pi/32}
    #pragma unroll 4
    for (int ny = 0; ny < 64; ny++) {
        float2 v = src[(size_t)ny * 256];
        accr[0] += v.x; acci[0] += v.y;
        float tc = wc, ts = ws;
        #pragma unroll
        for (int ky = 1; ky < 8; ky++) {
            accr[ky] += v.x * tc - v.y * ts;
            acci[ky] += v.x * ts + v.y * tc;
            float nt = tc * wc - ts * ws; ts = ts * wc + tc * ws; tc = nt;
        }
        float nw = wc * bc - ws * bs; ws = ws * bc + wc * bs; wc = nw;
    }
    float4* dst = (float4*)(a2 + ((size_t)(pair * 256 + t)) * 8);
    #pragma unroll
    for (int j = 0; j < 4; j++)
        dst[j] = make_float4(accr[2 * j], acci[2 * j], accr[2 * j + 1], acci[2 * j + 1]);
}

// ------- k_fx: forward x-DFT. block=(b,c): a2 -> xft[b][c][kz][ky][kx] -------
__global__ __launch_bounds__(256) void k_fx(const float2* __restrict__ a2,
                                            float2* __restrict__ xft) {
    __shared__ float lsr[4096], lsi[4096];    // [nx][kz*8+ky]
    int t = threadIdx.x;
    int b = blockIdx.x >> 5, c = blockIdx.x & 31;
    for (int u = 0; u < 16; u++) {
        int idx = u * 256 + t;                // nx*64 + kk
        int nx = idx >> 6, kk = idx & 63;
        float2 v = a2[((size_t)((b * 64 + nx) * 256 + c * 8)) * 8 + kk];
        lsr[idx] = v.x; lsi[idx] = v.y;
    }
    __syncthreads();
    for (int h = 0; h < 2; h++) {
        int f = h * 256 + t;                  // kz*64 + ky*8 + kx
        int kx = f & 7, kzky = f >> 3;
        float sn, cc; sincosf((float)kx * (PI_F / 32.0f), &sn, &cc);
        float bsn = -sn;                      // e^{-i kx pi/32}
        float tc = 1.0f, ts = 0.0f, rr = 0.0f, ri = 0.0f;
        for (int nx = 0; nx < 64; nx++) {
            float vr = lsr[nx * 64 + kzky], vi = lsi[nx * 64 + kzky];
            rr += vr * tc - vi * ts;
            ri += vr * ts + vi * tc;
            float nt = tc * cc - ts * bsn; ts = ts * cc + tc * bsn; tc = nt;
        }
        xft[((size_t)(b * 32 + c)) * 512 + f] = make_float2(rr, ri);
    }
}

// ---------------- mode mix per (b,kx,ky) ----------------
__global__ __launch_bounds__(256) void k_mix(const float2* __restrict__ xft,
        const float* __restrict__ wr, const float* __restrict__ wi,
        float2* __restrict__ yft) {
    __shared__ float2 lx[32 * 8];
    int t = threadIdx.x;
    int b = blockIdx.x >> 6;
    int kx = (blockIdx.x >> 3) & 7;
    int ky = blockIdx.x & 7;
    {
        int i = t >> 3, kz = t & 7;
        lx[t] = xft[((size_t)(b * 32 + i)) * 512 + kz * 64 + ky * 8 + kx];
    }
    __syncthreads();
    int o = t >> 3, kz = t & 7;
    float yr = 0.0f, yi = 0.0f;
    for (int i = 0; i < 32; i++) {
        float2 x = lx[i * 8 + kz];
        int wofs = ((i * 32 + o) << 9) + kx * 64 + ky * 8 + kz;   // w[i][o][kx][ky][kz]
        float wrv = wr[wofs], wiv = wi[wofs];
        yr += x.x * wrv - x.y * wiv;
        yi += x.x * wiv + x.y * wrv;
    }
    yft[((size_t)(b * 32 + o)) * 512 + kz * 64 + ky * 8 + kx] = make_float2(yr, yi);
}

// ------- k_ix: inverse-x only. yft -> b1[b][nx][o][kz][ky] (2 MB) -------
__global__ __launch_bounds__(256) void k_ix(const float2* __restrict__ yft,
                                            float2* __restrict__ b1) {
    __shared__ float2 ly[512 * 9];   // [oo*64+kz*8+ky][kx] padded
    int t = threadIdx.x;
    int b  = blockIdx.x >> 8;
    int nx = (blockIdx.x >> 2) & 63;
    int og = blockIdx.x & 3;
    const float2* src = yft + ((size_t)(b * 32 + og * 8)) * 512;
    for (int u = 0; u < 16; u++) {
        int g = u * 256 + t;         // (oo*64+kz*8+ky)*8 + kx
        ly[(g >> 3) * 9 + (g & 7)] = src[g];
    }
    __syncthreads();
    float cs, ss; sincosf((float)nx * (PI_F / 32.0f), &ss, &cs);
    float2* dst = b1 + ((size_t)(b * 64 + nx)) * 2048 + og * 512;
    for (int h = 0; h < 2; h++) {
        int idx = h * 256 + t;       // oo*64 + kz*8 + ky
        const float2* row = ly + idx * 9;
        float c = 1.0f, s = 0.0f, rr = 0.0f, ri = 0.0f;
        #pragma unroll
        for (int kx = 0; kx < 8; kx++) {
            float2 y = row[kx];
            rr += y.x * c - y.y * s;      // e^{+i kx nx θ}
            ri += y.x * s + y.y * c;
            float nc = c * cs - s * ss; s = s * cs + c * ss; c = nc;
        }
        dst[idx] = make_float2(rr, ri);
    }
}

// ------- k_fin: inverse-y + bypass + inverse-z + gelu + radix-8 fwd z-DFT -------
__global__ __launch_bounds__(256) void k_fin(
        const float* __restrict__ xin, const float2* __restrict__ b1,
        const float* __restrict__ wt, const float* __restrict__ bb,
        float* __restrict__ xout, float2* __restrict__ a1, int do_z) {
    __shared__ float S[9024];
    float* b1sr = S;                 // 8*264 = 2112 (dead after inv-y)
    float* b1si = S + 2112;          // 2112 -> region [0,4224)
    float* hr   = S;                 // 2144  (aliases b1s region, used after)
    float* hi   = S + 2144;          // 2144 -> [0,4288)
    float* xs   = S + 4288;          // 32*64 = 2048
    float2* ms  = (float2*)(S + 6336);   // 256 float2 = 512 floats
    float* ys   = S + 6848;          // 32*68 = 2176 -> total 9024
    int t = threadIdx.x;
    int b, nx, ny; swz8k(blockIdx.x, b, nx, ny);
    int nxy = nx * 64 + ny;

    const float* xb = xin + (((size_t)b * 32) << 18) + (nxy << 6);
    for (int u = 0; u < 2; u++) {
        int i4 = u * 256 + t;
        int ch = i4 >> 4, q = i4 & 15;
        float4 v = *(const float4*)(xb + ((size_t)ch << 18) + q * 4);
        *(float4*)(xs + ch * 64 + q * 4) = v;
    }
    const float2* bsrc = b1 + ((size_t)(b * 64 + nx)) * 2048;  // contiguous 16 KB
    for (int u = 0; u < 8; u++) {
        int g = u * 256 + t;         // (o*8+kz)*8 + ky
        float2 v = bsrc[g];
        int ky = g & 7, okz = g >> 3;
        b1sr[ky * 264 + okz] = v.x;
        b1si[ky * 264 + okz] = v.y;
    }
    __syncthreads();
    {   // inverse-y at this ny: thread t = o*8+kz
        float cs, ss; sincosf((float)ny * (PI_F / 32.0f), &ss, &cs);
        float c = 1.0f, s = 0.0f, mr = 0.0f, mi = 0.0f;
        #pragma unroll
        for (int ky = 0; ky < 8; ky++) {
            float vr = b1sr[ky * 264 + t], vi = b1si[ky * 264 + t];
            mr += vr * c - vi * s;        // e^{+i ky ny θ}
            mi += vr * s + vi * c;
            float nc = c * cs - s * ss; s = s * cs + c * ss; c = nc;
        }
        ms[t] = make_float2(mr, mi);
    }
    __syncthreads();

    int nz = t & 63;
    int wq = rfl(t >> 6);
    float c7[8], s7[8];
    c7[0] = 1.f; s7[0] = 0.f;
    {
        float cs, ss; sincosf((float)nz * (PI_F / 32.0f), &ss, &cs);
        #pragma unroll
        for (int kz = 1; kz < 8; kz++) {
            c7[kz] = c7[kz - 1] * cs - s7[kz - 1] * ss;
            s7[kz] = s7[kz - 1] * cs + c7[kz - 1] * ss;
        }
    }
    float acc[8];
    #pragma unroll
    for (int k = 0; k < 8; k++) acc[k] = bb[wq * 8 + k];        // s_load
    #pragma unroll 8
    for (int i = 0; i < 32; i++) {
        float xv = xs[i * 64 + nz];                             // conflict-free ds_read
        const float* wrow = wt + i * 32 + wq * 8;               // s_load_dwordx8
        #pragma unroll
        for (int k = 0; k < 8; k++) acc[k] += wrow[k] * xv;
    }
    const float scale = 1.0f / 262144.0f;
    size_t obase = (((size_t)b * 32) << 18) + (nxy << 6) + nz;
    #pragma unroll
    for (int k = 0; k < 8; k++) {
        int o = wq * 8 + k;
        const float2* mrow = ms + o * 8;                        // wave-uniform LDS
        float sp = mrow[0].x;
        #pragma unroll
        for (int kz = 1; kz < 8; kz++) {
            float2 m = mrow[kz];
            sp += 2.0f * (m.x * c7[kz] - m.y * s7[kz]);
        }
        float g = gelu_exact(sp * scale + acc[k]);
        xout[obase + ((size_t)o << 18)] = g;
        ys[o * 68 + nz] = g;
    }
    if (do_z) {
        __syncthreads();             // b1s region dead -> hr/hi may overwrite
        {   // radix-8 stage A: thread (o = t>>3, q = t&7)
            int o = t >> 3, q = t & 7;
            float h[8];
            #pragma unroll
            for (int p = 0; p < 8; p++) h[p] = ys[o * 68 + 8 * p + q];
            rdft8(h, hr, hi, o, q);
        }
        __syncthreads();
        {   // stage B: thread (o = t>>3, kz = t&7)
            float2 r = zdft_combine(hr, hi, t >> 3, t & 7);
            a1[((size_t)(b * 4096 + nxy)) * 256 + t] = r;       // coalesced
        }
    }
}

// ---------------- projection: weights via scalar loads, no LDS ----------------
__global__ void k_proj(const float* __restrict__ x4, const float* __restrict__ w1,
                       const float* __restrict__ b1, const float* __restrict__ w2,
                       const float* __restrict__ b2, const float* __restrict__ state_in,
                       float* __restrict__ out) {
    int t = threadIdx.x;
    int g = blockIdx.x * 256 + t;
    int b = rfl(g >> 18);
    int n = g & (262144 - 1);
    float xv[32];
    const float* xb = x4 + (((size_t)b * 32) << 18) + n;
    #pragma unroll 8
    for (int i = 0; i < 32; i++) xv[i] = xb[(size_t)i << 18];
    float h[32];
    for (int o = 0; o < 32; o++) {
        float a = b1[o];
        const float* w = w1 + o * 32;
        #pragma unroll
        for (int i = 0; i < 32; i++) a += w[i] * xv[i];
        h[o] = gelu_exact(a);
    }
    size_t base = ((size_t)b * 262144 + n) * 4;
    float4 sv = *(const float4*)(state_in + base);
    float r[4];
    for (int j = 0; j < 4; j++) {
        float a = b2[j];
        const float* w = w2 + j * 32;
        #pragma unroll
        for (int o = 0; o < 32; o++) a += w[o] * h[o];
        r[j] = a;
    }
    *(float4*)(out + base) = make_float4(sv.x + 0.05f * r[0], sv.y + 0.05f * r[1],
                                         sv.z + 0.05f * r[2], sv.w + 0.05f * r[3]);
}

extern "C" void kernel_launch(void* const* d_in, const int* in_sizes, int n_in,
                              void* d_out, int out_size, void* d_ws, size_t ws_size,
                              hipStream_t stream) {
    const float* state_in   = (const float*)d_in[0];
    const float* node_pos   = (const float*)d_in[1];
    const float* time_i     = (const float*)d_in[3];
    const float* conditions = (const float*)d_in[4];
    const float* t_embed_w  = (const float*)d_in[5];
    const float* t_embed_b  = (const float*)d_in[6];
    const float* c_embed_w  = (const float*)d_in[7];
    const float* c_embed_b  = (const float*)d_in[8];
    const float* lift_w     = (const float*)d_in[9];
    const float* lift_b     = (const float*)d_in[10];
    const float* spec_wr    = (const float*)d_in[11];
    const float* spec_wi    = (const float*)d_in[12];
    const float* byp_w      = (const float*)d_in[13];
    const float* byp_b      = (const float*)d_in[14];
    const float* proj1_w    = (const float*)d_in[15];
    const float* proj1_b    = (const float*)d_in[16];
    const float* proj2_w    = (const float*)d_in[17];
    const float* proj2_b    = (const float*)d_in[18];
    float* out = (float*)d_out;
    float* ws  = (float*)d_ws;

    float*  xA   = ws;                          // 16777216 floats
    float*  xB   = ws + 16777216;               // 16777216
    float2* a1   = (float2*)(ws + 33554432);    // 2097152 float2 -> ends 37748736
    float2* xft  = (float2*)(ws + 37748736);    // 32768 float2
    float2* yft  = (float2*)(ws + 37814272);    // 32768 float2
    float2* b1   = (float2*)(ws + 37879808);    // 262144 float2 -> ends 38404096
    float*  embk = ws + 38404096;               // 64
    float*  wtb  = ws + 38404160;               // 4096 -> 38408256
    float*  wlT  = ws + 38408256;               // 1184 -> 38409440
    float2* a2   = (float2*)(ws + 38409440);    // 262144 float2 -> ends 38933728

    k_emb<<<2, 256, 0, stream>>>(time_i, conditions, t_embed_w, t_embed_b,
                                 c_embed_w, c_embed_b, lift_b, embk);
    k_wt<<<21, 256, 0, stream>>>(byp_w, lift_w, wtb, wlT);
    k_lift<<<8192, 256, 0, stream>>>(state_in, node_pos, wlT, embk, xA, a1);

    for (int l = 0; l < 4; l++) {
        float* xin  = (l & 1) ? xB : xA;
        float* xout = (l & 1) ? xA : xB;
        k_fy<<<128, 256, 0, stream>>>(a1, a2);
        k_fx<<<64, 256, 0, stream>>>(a2, xft);
        k_mix<<<128, 256, 0, stream>>>(xft, spec_wr + (size_t)l * 524288,
                                       spec_wi + (size_t)l * 524288, yft);
        k_ix<<<512, 256, 0, stream>>>(yft, b1);
        k_fin<<<8192, 256, 0, stream>>>(xin, b1, wtb + l * 1024, byp_b + l * 32,
                                        xout, a1, (l < 3) ? 1 : 0);
    }

    k_proj<<<2048, 256, 0, stream>>>(xA, proj1_w, proj1_b, proj2_w, proj2_b, state_in, out);
}